// Round 4
// baseline (4490.076 us; speedup 1.0000x reference)
//
#include <hip/hip_runtime.h>

#define DEV __device__ __forceinline__

typedef short s8v __attribute__((ext_vector_type(8)));
typedef float f4v __attribute__((ext_vector_type(4)));

DEV short f2bf(float f) {
  unsigned u = __float_as_uint(f);
  u += 0x7FFFu + ((u >> 16) & 1u);
  return (short)(u >> 16);
}
DEV float bf2f(short s) { return __uint_as_float(((unsigned)(unsigned short)s) << 16); }

DEV void gld_lds16(const short* g, short* l) {
  __builtin_amdgcn_global_load_lds(
      (const __attribute__((address_space(1))) void*)g,
      (__attribute__((address_space(3))) void*)l, 16, 0, 0);
}

// XCD-bijective swizzle (m204)
DEV int xcd_swz(int id, int nwg) {
  int q8 = nwg >> 3, r8 = nwg & 7, xcd = id & 7, off = id >> 3;
  return (xcd < r8) ? (xcd * (q8 + 1) + off) : (r8 * (q8 + 1) + (xcd - r8) * q8 + off);
}

// ================= 256x256 8-wave phase-split bf16 BT GEMM =================
// C[M,N] = epi(A[M,K] @ B[N,K]^T). A,B bf16 row-major (lda,ldb elems, %8==0).
// Requires: N%256==0, K%64==0; A must be readable up to row ceil(M/256)*256.
// flags: 1=+bias[col], 2=exact GELU, 4=accumulate into fp32 C, 8=bf16 out
__global__ __launch_bounds__(512, 2) void gemm256(
    const short* __restrict__ A, const short* __restrict__ B, void* __restrict__ Cv,
    const float* __restrict__ bias,
    int M, int N, int K, int lda, int ldb, int ldc, int flags)
{
  __shared__ __align__(16) short As[2][256 * 64];
  __shared__ __align__(16) short Bs[2][256 * 64];
  int nwg = gridDim.x * gridDim.y;
  int idl = blockIdx.y * gridDim.x + blockIdx.x;
  int swz = xcd_swz(idl, nwg);
  int bx = swz % gridDim.x, by = swz / gridDim.x;
  int m0 = by * 256, n0 = bx * 256;
  int tid = threadIdx.x, lane = tid & 63, wid = tid >> 6;
  int wr = wid >> 2, wc = wid & 3;            // 2 x 4 wave grid
  int lr = lane & 15, kg = lane >> 4;
  int d0 = wid * 64 + lane;                   // staging chunk id base (16B units)

  f4v acc[8][4] = {};
  int NT = K >> 6;

  // ---- staging: linear LDS dest, pre-swizzled global source (st_16x32) ----
  // logical chunk y = d ^ (((d>>5)&1)<<1)  (byte bit5 ^= bit9; involution)
  #define STAGE(bufi, k0)                                                     \
    {                                                                         \
      _Pragma("unroll")                                                       \
      for (int i = 0; i < 4; ++i) {                                           \
        int d = i * 512 + d0;                                                 \
        int y = d ^ (((d >> 5) & 1) << 1);                                    \
        int row = y >> 3, c = y & 7;                                          \
        gld_lds16(A + (long)(m0 + row) * lda + k0 + c * 8,                    \
                  &As[bufi][(i * 512 + wid * 64) * 8]);                       \
        gld_lds16(B + (long)(n0 + row) * ldb + k0 + c * 8,                    \
                  &Bs[bufi][(i * 512 + wid * 64) * 8]);                       \
      }                                                                       \
    }

  STAGE(0, 0)
  asm volatile("s_waitcnt vmcnt(0)" ::: "memory");
  __builtin_amdgcn_s_barrier();

  for (int t = 0; t < NT; ++t) {
    int buf = t & 1;
    s8v bfr[4][2];
    #pragma unroll
    for (int p = 0; p < 4; ++p) {
      s8v afr[2][2];
      #pragma unroll
      for (int mi2 = 0; mi2 < 2; ++mi2)
        #pragma unroll
        for (int ks = 0; ks < 2; ++ks) {
          int row = wr * 128 + (p * 2 + mi2) * 16 + lr;
          int c = (ks * 4 + kg) ^ ((row >> 1) & 2);     // read-side swizzle
          afr[mi2][ks] = *(const s8v*)&As[buf][row * 64 + c * 8];
        }
      if (p == 0) {
        #pragma unroll
        for (int ni = 0; ni < 4; ++ni)
          #pragma unroll
          for (int ks = 0; ks < 2; ++ks) {
            int row = wc * 64 + ni * 16 + lr;
            int c = (ks * 4 + kg) ^ ((row >> 1) & 2);
            bfr[ni][ks] = *(const s8v*)&Bs[buf][row * 64 + c * 8];
          }
        if (t + 1 < NT) STAGE(buf ^ 1, (t + 1) * 64)
      }
      __builtin_amdgcn_s_barrier();
      __builtin_amdgcn_s_setprio(1);
      #pragma unroll
      for (int mi2 = 0; mi2 < 2; ++mi2)
        #pragma unroll
        for (int ni = 0; ni < 4; ++ni)
          #pragma unroll
          for (int ks = 0; ks < 2; ++ks)
            acc[p * 2 + mi2][ni] = __builtin_amdgcn_mfma_f32_16x16x32_bf16(
                afr[mi2][ks], bfr[ni][ks], acc[p * 2 + mi2][ni], 0, 0, 0);
      __builtin_amdgcn_s_setprio(0);
      __builtin_amdgcn_s_barrier();
    }
    // next buffer's stage (issued 4 phases ago) must land before next tile
    asm volatile("s_waitcnt vmcnt(0)" ::: "memory");
    __builtin_amdgcn_s_barrier();
  }
  #undef STAGE

  float* Cf = (float*)Cv;
  short* Cb = (short*)Cv;
  #pragma unroll
  for (int mi = 0; mi < 8; ++mi)
    #pragma unroll
    for (int ni = 0; ni < 4; ++ni) {
      int col = n0 + wc * 64 + ni * 16 + lr;
      float bvv = (flags & 1) ? bias[col] : 0.f;
      #pragma unroll
      for (int j = 0; j < 4; ++j) {
        int row = m0 + wr * 128 + mi * 16 + kg * 4 + j;
        if (row >= M) continue;
        float v = acc[mi][ni][j] + bvv;
        if (flags & 2) v = 0.5f * v * (1.f + erff(v * 0.70710678118f));
        long ci = (long)row * ldc + col;
        if (flags & 8) Cb[ci] = f2bf(v);
        else { if (flags & 4) v += Cf[ci]; Cf[ci] = v; }
      }
    }
}

// ---------------- fused flash attention ----------------
// qkv: [4][1025][1536] bf16 (Q +0, K +64, V +128 per head zh*192)
// O:   [4][1025][512]  bf16
__global__ __launch_bounds__(256) void flash_k(
    const short* __restrict__ qkv, short* __restrict__ O)
{
  int swz = xcd_swz(blockIdx.x, 544);
  int z = swz / 17, qt = swz - z * 17;
  int zb = z >> 3, zh = z & 7;
  const short* base = qkv + (long)zb * 1025 * 1536 + zh * 192;
  const short* Qg = base;
  const short* Kg = base + 64;
  const short* Vg = base + 128;
  int q0 = qt * 64;
  int tid = threadIdx.x, lane = tid & 63, w = tid >> 6;
  int lr = lane & 15, kg = lane >> 4;

  __shared__ __align__(16) short Qs[64][72];
  __shared__ __align__(16) short Ks[64 * 64];
  __shared__ __align__(16) short Vt[64][72];
  __shared__ __align__(16) short Ps[4][16][72];

  for (int s = tid; s < 512; s += 256) {
    int row = s >> 3, ch = s & 7;
    s8v v = {};
    if (q0 + row < 1025) v = *(const s8v*)(Qg + (long)(q0 + row) * 1536 + ch * 8);
    *(s8v*)&Qs[row][ch * 8] = v;
  }
  __syncthreads();
  s8v aq[2];
  aq[0] = *(const s8v*)&Qs[w * 16 + lr][kg * 8];
  aq[1] = *(const s8v*)&Qs[w * 16 + lr][32 + kg * 8];

  f4v acc[4] = {};
  float m_run[4], l_run[4];
  #pragma unroll
  for (int j = 0; j < 4; ++j) { m_run[j] = -3.0e38f; l_run[j] = 0.f; }

  for (int kt = 0; kt < 17; ++kt) {
    int kv0 = kt * 64;
    __syncthreads();
    {
      int s0 = w * 128;
      #pragma unroll
      for (int i = 0; i < 2; ++i) {
        int s = s0 + i * 64 + lane;
        int row = s >> 3, c = s & 7;
        int cg = c ^ (row & 7);
        gld_lds16(Kg + (long)(kv0 + row) * 1536 + cg * 8, Ks + (s0 + i * 64) * 8);
      }
    }
    #pragma unroll
    for (int p = 0; p < 2; ++p) {
      int s = p * 256 + tid;
      int key = s & 63, ch = s >> 6;
      s8v v = {};
      if (kv0 + key < 1025) v = *(const s8v*)(Vg + (long)(kv0 + key) * 1536 + ch * 8);
      #pragma unroll
      for (int j = 0; j < 8; ++j) Vt[ch * 8 + j][key] = v[j];
    }
    __syncthreads();

    f4v sa[4] = {};
    #pragma unroll
    for (int ni = 0; ni < 4; ++ni) {
      int row = ni * 16 + lr;
      #pragma unroll
      for (int ks = 0; ks < 2; ++ks) {
        int c = (ks * 4 + kg) ^ (row & 7);
        s8v bk = *(const s8v*)(Ks + row * 64 + c * 8);
        sa[ni] = __builtin_amdgcn_mfma_f32_16x16x32_bf16(aq[ks], bk, sa[ni], 0, 0, 0);
      }
    }
    float sv[4][4], pv[4][4], tm[4], ts[4];
    #pragma unroll
    for (int j = 0; j < 4; ++j) tm[j] = -3.0e38f;
    #pragma unroll
    for (int ni = 0; ni < 4; ++ni) {
      bool valid = (kv0 + ni * 16 + lr) < 1025;
      #pragma unroll
      for (int j = 0; j < 4; ++j) {
        float s = valid ? sa[ni][j] * 0.125f : -3.0e38f;
        sv[ni][j] = s;
        tm[j] = fmaxf(tm[j], s);
      }
    }
    #pragma unroll
    for (int o = 1; o < 16; o <<= 1)
      #pragma unroll
      for (int j = 0; j < 4; ++j) tm[j] = fmaxf(tm[j], __shfl_xor(tm[j], o));
    float scale[4], m_new[4];
    #pragma unroll
    for (int j = 0; j < 4; ++j) {
      m_new[j] = fmaxf(m_run[j], tm[j]);
      scale[j] = __expf(m_run[j] - m_new[j]);
      m_run[j] = m_new[j];
      ts[j] = 0.f;
    }
    #pragma unroll
    for (int ni = 0; ni < 4; ++ni)
      #pragma unroll
      for (int j = 0; j < 4; ++j) {
        float p = __expf(sv[ni][j] - m_new[j]);
        pv[ni][j] = p;
        ts[j] += p;
      }
    #pragma unroll
    for (int o = 1; o < 16; o <<= 1)
      #pragma unroll
      for (int j = 0; j < 4; ++j) ts[j] += __shfl_xor(ts[j], o);
    #pragma unroll
    for (int j = 0; j < 4; ++j) l_run[j] = l_run[j] * scale[j] + ts[j];
    #pragma unroll
    for (int ni = 0; ni < 4; ++ni)
      #pragma unroll
      for (int j = 0; j < 4; ++j) acc[ni][j] *= scale[j];
    #pragma unroll
    for (int ni = 0; ni < 4; ++ni)
      #pragma unroll
      for (int j = 0; j < 4; ++j)
        Ps[w][kg * 4 + j][ni * 16 + lr] = f2bf(pv[ni][j]);
    asm volatile("s_waitcnt lgkmcnt(0)" ::: "memory");
    s8v ap[2];
    ap[0] = *(const s8v*)&Ps[w][lr][kg * 8];
    ap[1] = *(const s8v*)&Ps[w][lr][32 + kg * 8];
    #pragma unroll
    for (int ni = 0; ni < 4; ++ni) {
      #pragma unroll
      for (int ks = 0; ks < 2; ++ks) {
        s8v bvv = *(const s8v*)&Vt[ni * 16 + lr][ks * 32 + kg * 8];
        acc[ni] = __builtin_amdgcn_mfma_f32_16x16x32_bf16(ap[ks], bvv, acc[ni], 0, 0, 0);
      }
    }
  }
  float inv[4];
  #pragma unroll
  for (int j = 0; j < 4; ++j) inv[j] = 1.f / l_run[j];
  #pragma unroll
  for (int ni = 0; ni < 4; ++ni)
    #pragma unroll
    for (int j = 0; j < 4; ++j) {
      int row = q0 + w * 16 + kg * 4 + j;
      if (row < 1025)
        O[((long)(zb * 1025 + row)) * 512 + zh * 64 + ni * 16 + lr] = f2bf(acc[ni][j] * inv[j]);
    }
}

// ---------------- transpose+convert: w[K][N] fp32 -> wt[N][K] bf16 ----------------
__global__ __launch_bounds__(256) void tconv_k(const float* __restrict__ w,
    short* __restrict__ wt, int K, int N)
{
  __shared__ float tile[32][33];
  int n0 = blockIdx.x * 32, k0 = blockIdx.y * 32;
  int tx = threadIdx.x & 31, ty = threadIdx.x >> 5;
  #pragma unroll
  for (int j = 0; j < 4; ++j)
    tile[ty + j * 8][tx] = w[(long)(k0 + ty + j * 8) * N + n0 + tx];
  __syncthreads();
  #pragma unroll
  for (int j = 0; j < 4; ++j)
    wt[(long)(n0 + ty + j * 8) * K + k0 + tx] = f2bf(tile[tx][ty + j * 8]);
}

// ---------------- elementwise fp32 -> bf16 ----------------
__global__ __launch_bounds__(256) void cvt_k(const float* __restrict__ in,
    short* __restrict__ out, int n)
{
  int i = blockIdx.x * 256 + threadIdx.x;
  if (i < n) out[i] = f2bf(in[i]);
}

// ---------------- LayerNorm D=768 ----------------
DEV void st_ln(float* p, float v) { *p = v; }
DEV void st_ln(short* p, float v) { *p = f2bf(v); }

template<typename OT>
__global__ __launch_bounds__(256) void ln_k(const float* __restrict__ x,
    const float* __restrict__ g, const float* __restrict__ b,
    OT* __restrict__ y, int rows)
{
  int row = blockIdx.x;
  if (row >= rows) return;
  const float* xr = x + (long)row * 768;
  OT* yr = y + (long)row * 768;
  int t = threadIdx.x;
  float v0 = xr[t], v1 = xr[t + 256], v2 = xr[t + 512];
  float s = v0 + v1 + v2, s2 = v0 * v0 + v1 * v1 + v2 * v2;
  #pragma unroll
  for (int o = 32; o > 0; o >>= 1) { s += __shfl_down(s, o); s2 += __shfl_down(s2, o); }
  __shared__ float as_[4], as2_[4];
  if ((t & 63) == 0) { as_[t >> 6] = s; as2_[t >> 6] = s2; }
  __syncthreads();
  s = as_[0] + as_[1] + as_[2] + as_[3];
  s2 = as2_[0] + as2_[1] + as2_[2] + as2_[3];
  float mean = s * (1.f / 768.f);
  float var = s2 * (1.f / 768.f) - mean * mean;
  float r = rsqrtf(var + 1e-5f);
  st_ln(&yr[t],       (v0 - mean) * r * g[t]       + b[t]);
  st_ln(&yr[t + 256], (v1 - mean) * r * g[t + 256] + b[t + 256]);
  st_ln(&yr[t + 512], (v2 - mean) * r * g[t + 512] + b[t + 512]);
}

// ---------------- patch extraction ----------------
__global__ __launch_bounds__(256) void im2col_k(const float* __restrict__ x,
    short* __restrict__ A)
{
  int i = blockIdx.x * 256 + threadIdx.x;
  int k = i & 255, row = i >> 8;
  int px = k & 15, py = k >> 4;
  int gx = row & 31, gy = (row >> 5) & 31, b = row >> 10;
  A[i] = f2bf(x[((long)(b * 512) + gy * 16 + py) * 512 + gx * 16 + px]);
}

// ---------------- t = concat(cls, tok) + pos ----------------
__global__ __launch_bounds__(256) void assemble_k(const short* __restrict__ tok,
    const float* __restrict__ cls, const float* __restrict__ pos, float* __restrict__ t)
{
  int i = blockIdx.x * 256 + threadIdx.x;
  int d = i % 768; int rn = i / 768; int n = rn % 1025; int b = rn / 1025;
  float v = (n == 0) ? cls[d] : bf2f(tok[((long)(b * 1024 + n - 1)) * 768 + d]);
  t[i] = v + pos[n * 768 + d];
}

extern "C" void kernel_launch(void* const* d_in, const int* in_sizes, int n_in,
                              void* d_out, int out_size, void* d_ws, size_t ws_size,
                              hipStream_t stream)
{
  const float* x       = (const float*)d_in[0];
  const float* conv_w  = (const float*)d_in[1];
  const float* conv_b  = (const float*)d_in[2];
  const float* cls     = (const float*)d_in[3];
  const float* pos     = (const float*)d_in[4];
  const float* qkv_w   = (const float*)d_in[5];
  const float* merge_w = (const float*)d_in[6];
  const float* merge_b = (const float*)d_in[7];
  const float* ln1_s   = (const float*)d_in[8];
  const float* ln1_b   = (const float*)d_in[9];
  const float* ln2_s   = (const float*)d_in[10];
  const float* ln2_b   = (const float*)d_in[11];
  const float* ffn_w1  = (const float*)d_in[12];
  const float* ffn_b1  = (const float*)d_in[13];
  const float* ffn_w2  = (const float*)d_in[14];
  const float* ffn_b2  = (const float*)d_in[15];
  const float* lnf_s   = (const float*)d_in[16];
  const float* lnf_b   = (const float*)d_in[17];

  char* wsp = (char*)d_ws;
  size_t o = 0;
  auto take = [&](size_t bytes) { char* r = wsp + o; o = (o + bytes + 255) & ~(size_t)255; return r; };
  short* wq   = (short*)take(1536ul * 768 * 2);
  short* wm   = (short*)take(768ul * 512 * 2);
  short* wf1  = (short*)take(2048ul * 768 * 2);
  short* wf2  = (short*)take(768ul * 2048 * 2);
  short* wcv  = (short*)take(768ul * 256 * 2);
  float* t    = (float*)take(4100ul * 768 * 4);
  char*  hO   = take(4352ul * 768 * 2);              // h bf16 OR O bf16 (rows padded to 4352)
  short* qkv  = (short*)take(4ul * 1025 * 1536 * 2);
  char*  fV   = take(4352ul * 2048 * 2);             // f (padded) OR (im2col + tok)
  take(2ul << 20);                                   // slack

  short* h   = (short*)hO;
  short* O   = (short*)hO;
  short* f   = (short*)fV;
  short* imc = (short*)fV;
  short* tok = (short*)(fV + 4096ul * 256 * 2);

  dim3 blk(256), blk512(512);

  // ---- patch embed ----
  cvt_k<<<768, blk, 0, stream>>>(conv_w, wcv, 768 * 256);
  im2col_k<<<4096, blk, 0, stream>>>(x, imc);
  gemm256<<<dim3(3, 16), blk512, 0, stream>>>(imc, wcv, tok, conv_b,
      4096, 768, 256, 256, 256, 768, 1 | 8);
  assemble_k<<<12300, blk, 0, stream>>>(tok, cls, pos, t);

  for (int i = 0; i < 12; ++i) {
    tconv_k<<<dim3(48, 24), blk, 0, stream>>>(qkv_w + (long)i * 768 * 1536, wq, 768, 1536);
    tconv_k<<<dim3(24, 16), blk, 0, stream>>>(merge_w + (long)i * 512 * 768, wm, 512, 768);
    tconv_k<<<dim3(64, 24), blk, 0, stream>>>(ffn_w1 + (long)i * 768 * 2048, wf1, 768, 2048);
    tconv_k<<<dim3(24, 64), blk, 0, stream>>>(ffn_w2 + (long)i * 2048 * 768, wf2, 2048, 768);

    // h = LN1(t)
    ln_k<short><<<4100, blk, 0, stream>>>(t, ln1_s + i * 768, ln1_b + i * 768, h, 4100);
    // qkv = h @ qkv_w
    gemm256<<<dim3(6, 17), blk512, 0, stream>>>(h, wq, qkv, nullptr,
        4100, 1536, 768, 768, 768, 1536, 8);
    // fused attention -> O
    flash_k<<<544, blk, 0, stream>>>(qkv, O);
    // t += O @ merge_w + merge_b
    gemm256<<<dim3(3, 17), blk512, 0, stream>>>(O, wm, t, merge_b + i * 768,
        4100, 768, 512, 512, 512, 768, 1 | 4);
    // h = LN2(t)
    ln_k<short><<<4100, blk, 0, stream>>>(t, ln2_s + i * 768, ln2_b + i * 768, h, 4100);
    // f = GELU(h @ ffn_w1 + b1)
    gemm256<<<dim3(8, 17), blk512, 0, stream>>>(h, wf1, f, ffn_b1 + i * 2048,
        4100, 2048, 768, 768, 768, 2048, 1 | 2 | 8);
    // t += f @ ffn_w2 + b2
    gemm256<<<dim3(3, 17), blk512, 0, stream>>>(f, wf2, t, ffn_b2 + i * 768,
        4100, 768, 2048, 2048, 2048, 768, 1 | 4);
  }
  ln_k<float><<<4100, blk, 0, stream>>>(t, lnf_s, lnf_b, (float*)d_out, 4100);
}

// Round 5
// 2537.234 us; speedup vs baseline: 1.7697x; 1.7697x over previous
//
#include <hip/hip_runtime.h>

#define DEV __device__ __forceinline__

typedef short s8v __attribute__((ext_vector_type(8)));
typedef float f4v __attribute__((ext_vector_type(4)));

DEV short f2bf(float f) {
  unsigned u = __float_as_uint(f);
  u += 0x7FFFu + ((u >> 16) & 1u);
  return (short)(u >> 16);
}
DEV float bf2f(short s) { return __uint_as_float(((unsigned)(unsigned short)s) << 16); }

DEV void gld_lds16(const short* g, short* l) {
  __builtin_amdgcn_global_load_lds(
      (const __attribute__((address_space(1))) void*)g,
      (__attribute__((address_space(3))) void*)l, 16, 0, 0);
}

// XCD-bijective swizzle (m204)
DEV int xcd_swz(int id, int nwg) {
  int q8 = nwg >> 3, r8 = nwg & 7, xcd = id & 7, off = id >> 3;
  return (xcd < r8) ? (xcd * (q8 + 1) + off) : (r8 * (q8 + 1) + (xcd - r8) * q8 + off);
}

// ================= 64x128 tile bf16 BT GEMM =================
// C[M,N] = epi(A[M,K] @ B[N,K]^T). A,B bf16 row-major (%8 lda/ldb).
// Requires N%128==0, K%64==0; A readable through row ceil(M/64)*64.
// flags: 1=+bias[col], 2=exact GELU, 4=accumulate into fp32 C, 8=bf16 out
__global__ __launch_bounds__(256) void gemm64(
    const short* __restrict__ A, const short* __restrict__ B, void* __restrict__ Cv,
    const float* __restrict__ bias,
    int M, int N, int K, int lda, int ldb, int ldc, int flags)
{
  __shared__ __align__(16) short As[64 * 64];    // 8 KB
  __shared__ __align__(16) short Bs[128 * 64];   // 16 KB
  int nwg = gridDim.x * gridDim.y;
  int idl = blockIdx.y * gridDim.x + blockIdx.x;
  int swz = xcd_swz(idl, nwg);
  int bx = swz % gridDim.x, by = swz / gridDim.x;
  int m0 = by * 64, n0 = bx * 128;
  int tid = threadIdx.x, lane = tid & 63, w = tid >> 6;
  int lr = lane & 15, kg = lane >> 4;
  f4v acc[4][2] = {};
  for (int k0 = 0; k0 < K; k0 += 64) {
    #pragma unroll
    for (int p = 0; p < 2; ++p) {
      int ch = p * 256 + w * 64 + lane;
      int row = ch >> 3, c = ch & 7;
      gld_lds16(A + (long)(m0 + row) * lda + k0 + c * 8, As + (p * 256 + w * 64) * 8);
    }
    #pragma unroll
    for (int p = 0; p < 4; ++p) {
      int ch = p * 256 + w * 64 + lane;
      int row = ch >> 3, c = ch & 7;
      gld_lds16(B + (long)(n0 + row) * ldb + k0 + c * 8, Bs + (p * 256 + w * 64) * 8);
    }
    __syncthreads();
    #pragma unroll
    for (int ks = 0; ks < 2; ++ks) {
      s8v av[4], bv[2];
      #pragma unroll
      for (int mi = 0; mi < 4; ++mi)
        av[mi] = *(const s8v*)&As[(mi * 16 + lr) * 64 + ks * 32 + kg * 8];
      #pragma unroll
      for (int ni = 0; ni < 2; ++ni)
        bv[ni] = *(const s8v*)&Bs[(w * 32 + ni * 16 + lr) * 64 + ks * 32 + kg * 8];
      #pragma unroll
      for (int mi = 0; mi < 4; ++mi)
        #pragma unroll
        for (int ni = 0; ni < 2; ++ni)
          acc[mi][ni] = __builtin_amdgcn_mfma_f32_16x16x32_bf16(av[mi], bv[ni], acc[mi][ni], 0, 0, 0);
    }
    __syncthreads();
  }
  float* Cf = (float*)Cv;
  short* Cb = (short*)Cv;
  #pragma unroll
  for (int mi = 0; mi < 4; ++mi)
    #pragma unroll
    for (int ni = 0; ni < 2; ++ni) {
      int col = n0 + w * 32 + ni * 16 + lr;
      float bvv = (flags & 1) ? bias[col] : 0.f;
      #pragma unroll
      for (int j = 0; j < 4; ++j) {
        int row = m0 + mi * 16 + kg * 4 + j;
        if (row >= M) continue;
        float v = acc[mi][ni][j] + bvv;
        if (flags & 2) v = 0.5f * v * (1.f + erff(v * 0.70710678118f));
        long ci = (long)row * ldc + col;
        if (flags & 8) Cb[ci] = f2bf(v);
        else { if (flags & 4) v += Cf[ci]; Cf[ci] = v; }
      }
    }
}

// ---------------- fused flash attention ----------------
// qkv: [4][1025][1536] bf16 (Q +0, K +64, V +128 per head zh*192)
// O:   [4][1025][512]  bf16
__global__ __launch_bounds__(256) void flash_k(
    const short* __restrict__ qkv, short* __restrict__ O)
{
  int swz = xcd_swz(blockIdx.x, 544);
  int z = swz / 17, qt = swz - z * 17;
  int zb = z >> 3, zh = z & 7;
  const short* base = qkv + (long)zb * 1025 * 1536 + zh * 192;
  const short* Qg = base;
  const short* Kg = base + 64;
  const short* Vg = base + 128;
  int q0 = qt * 64;
  int tid = threadIdx.x, lane = tid & 63, w = tid >> 6;
  int lr = lane & 15, kg = lane >> 4;

  __shared__ __align__(16) short Qs[64][72];
  __shared__ __align__(16) short Ks[64 * 64];
  __shared__ __align__(16) short Vt[64][72];
  __shared__ __align__(16) short Ps[4][16][72];

  for (int s = tid; s < 512; s += 256) {
    int row = s >> 3, ch = s & 7;
    s8v v = {};
    if (q0 + row < 1025) v = *(const s8v*)(Qg + (long)(q0 + row) * 1536 + ch * 8);
    *(s8v*)&Qs[row][ch * 8] = v;
  }
  __syncthreads();
  s8v aq[2];
  aq[0] = *(const s8v*)&Qs[w * 16 + lr][kg * 8];
  aq[1] = *(const s8v*)&Qs[w * 16 + lr][32 + kg * 8];

  f4v acc[4] = {};
  float m_run[4], l_run[4];
  #pragma unroll
  for (int j = 0; j < 4; ++j) { m_run[j] = -3.0e38f; l_run[j] = 0.f; }

  for (int kt = 0; kt < 17; ++kt) {
    int kv0 = kt * 64;
    __syncthreads();
    {
      int s0 = w * 128;
      #pragma unroll
      for (int i = 0; i < 2; ++i) {
        int s = s0 + i * 64 + lane;
        int row = s >> 3, c = s & 7;
        int cg = c ^ (row & 7);
        gld_lds16(Kg + (long)(kv0 + row) * 1536 + cg * 8, Ks + (s0 + i * 64) * 8);
      }
    }
    #pragma unroll
    for (int p = 0; p < 2; ++p) {
      int s = p * 256 + tid;
      int key = s & 63, ch = s >> 6;
      s8v v = {};
      if (kv0 + key < 1025) v = *(const s8v*)(Vg + (long)(kv0 + key) * 1536 + ch * 8);
      #pragma unroll
      for (int j = 0; j < 8; ++j) Vt[ch * 8 + j][key] = v[j];
    }
    __syncthreads();

    f4v sa[4] = {};
    #pragma unroll
    for (int ni = 0; ni < 4; ++ni) {
      int row = ni * 16 + lr;
      #pragma unroll
      for (int ks = 0; ks < 2; ++ks) {
        int c = (ks * 4 + kg) ^ (row & 7);
        s8v bk = *(const s8v*)(Ks + row * 64 + c * 8);
        sa[ni] = __builtin_amdgcn_mfma_f32_16x16x32_bf16(aq[ks], bk, sa[ni], 0, 0, 0);
      }
    }
    float sv[4][4], pv[4][4], tm[4], ts[4];
    #pragma unroll
    for (int j = 0; j < 4; ++j) tm[j] = -3.0e38f;
    #pragma unroll
    for (int ni = 0; ni < 4; ++ni) {
      bool valid = (kv0 + ni * 16 + lr) < 1025;
      #pragma unroll
      for (int j = 0; j < 4; ++j) {
        float s = valid ? sa[ni][j] * 0.125f : -3.0e38f;
        sv[ni][j] = s;
        tm[j] = fmaxf(tm[j], s);
      }
    }
    #pragma unroll
    for (int o = 1; o < 16; o <<= 1)
      #pragma unroll
      for (int j = 0; j < 4; ++j) tm[j] = fmaxf(tm[j], __shfl_xor(tm[j], o));
    float scale[4], m_new[4];
    #pragma unroll
    for (int j = 0; j < 4; ++j) {
      m_new[j] = fmaxf(m_run[j], tm[j]);
      scale[j] = __expf(m_run[j] - m_new[j]);
      m_run[j] = m_new[j];
      ts[j] = 0.f;
    }
    #pragma unroll
    for (int ni = 0; ni < 4; ++ni)
      #pragma unroll
      for (int j = 0; j < 4; ++j) {
        float p = __expf(sv[ni][j] - m_new[j]);
        pv[ni][j] = p;
        ts[j] += p;
      }
    #pragma unroll
    for (int o = 1; o < 16; o <<= 1)
      #pragma unroll
      for (int j = 0; j < 4; ++j) ts[j] += __shfl_xor(ts[j], o);
    #pragma unroll
    for (int j = 0; j < 4; ++j) l_run[j] = l_run[j] * scale[j] + ts[j];
    #pragma unroll
    for (int ni = 0; ni < 4; ++ni)
      #pragma unroll
      for (int j = 0; j < 4; ++j) acc[ni][j] *= scale[j];
    #pragma unroll
    for (int ni = 0; ni < 4; ++ni)
      #pragma unroll
      for (int j = 0; j < 4; ++j)
        Ps[w][kg * 4 + j][ni * 16 + lr] = f2bf(pv[ni][j]);
    asm volatile("s_waitcnt lgkmcnt(0)" ::: "memory");
    s8v ap[2];
    ap[0] = *(const s8v*)&Ps[w][lr][kg * 8];
    ap[1] = *(const s8v*)&Ps[w][lr][32 + kg * 8];
    #pragma unroll
    for (int ni = 0; ni < 4; ++ni) {
      #pragma unroll
      for (int ks = 0; ks < 2; ++ks) {
        s8v bvv = *(const s8v*)&Vt[ni * 16 + lr][ks * 32 + kg * 8];
        acc[ni] = __builtin_amdgcn_mfma_f32_16x16x32_bf16(ap[ks], bvv, acc[ni], 0, 0, 0);
      }
    }
  }
  float inv[4];
  #pragma unroll
  for (int j = 0; j < 4; ++j) inv[j] = 1.f / l_run[j];
  #pragma unroll
  for (int ni = 0; ni < 4; ++ni)
    #pragma unroll
    for (int j = 0; j < 4; ++j) {
      int row = q0 + w * 16 + kg * 4 + j;
      if (row < 1025)
        O[((long)(zb * 1025 + row)) * 512 + zh * 64 + ni * 16 + lr] = f2bf(acc[ni][j] * inv[j]);
    }
}

// ---------------- fused per-layer weight transpose+convert ----------------
// 4 weights: [K][N] fp32 -> [N][K] bf16. 32x32 tiles, flat block id.
DEV void tconv_body(const float* w, short* wt, int K, int N, int bx, int by, int tid)
{
  __shared__ float tile[32][33];
  int n0 = bx * 32, k0 = by * 32;
  int tx = tid & 31, ty = tid >> 5;
  #pragma unroll
  for (int j = 0; j < 4; ++j)
    tile[ty + j * 8][tx] = w[(long)(k0 + ty + j * 8) * N + n0 + tx];
  __syncthreads();
  #pragma unroll
  for (int j = 0; j < 4; ++j)
    wt[(long)(n0 + ty + j * 8) * K + k0 + tx] = f2bf(tile[tx][ty + j * 8]);
}

// zones: wq 48x24=1152 | wm 24x16=384 | wf1 64x24=1536 | wf2 24x64=1536  (total 4608)
__global__ __launch_bounds__(256) void tconv4_k(
    const float* __restrict__ sq, const float* __restrict__ sm,
    const float* __restrict__ sf1, const float* __restrict__ sf2,
    short* __restrict__ dq, short* __restrict__ dm,
    short* __restrict__ df1, short* __restrict__ df2)
{
  int id = blockIdx.x, tid = threadIdx.x;
  if (id < 1152)       tconv_body(sq,  dq,  768, 1536, id % 48,          id / 48,          tid);
  else if (id < 1536)  tconv_body(sm,  dm,  512, 768,  (id - 1152) % 24, (id - 1152) / 24, tid);
  else if (id < 3072)  tconv_body(sf1, df1, 768, 2048, (id - 1536) % 64, (id - 1536) / 64, tid);
  else                 tconv_body(sf2, df2, 2048, 768, (id - 3072) % 24, (id - 3072) / 24, tid);
}

// ---------------- elementwise fp32 -> bf16 ----------------
__global__ __launch_bounds__(256) void cvt_k(const float* __restrict__ in,
    short* __restrict__ out, int n)
{
  int i = blockIdx.x * 256 + threadIdx.x;
  if (i < n) out[i] = f2bf(in[i]);
}

// ---------------- LayerNorm D=768 ----------------
DEV void st_ln(float* p, float v) { *p = v; }
DEV void st_ln(short* p, float v) { *p = f2bf(v); }

template<typename OT>
__global__ __launch_bounds__(256) void ln_k(const float* __restrict__ x,
    const float* __restrict__ g, const float* __restrict__ b,
    OT* __restrict__ y, int rows)
{
  int row = blockIdx.x;
  if (row >= rows) return;
  const float* xr = x + (long)row * 768;
  OT* yr = y + (long)row * 768;
  int t = threadIdx.x;
  float v0 = xr[t], v1 = xr[t + 256], v2 = xr[t + 512];
  float s = v0 + v1 + v2, s2 = v0 * v0 + v1 * v1 + v2 * v2;
  #pragma unroll
  for (int o = 32; o > 0; o >>= 1) { s += __shfl_down(s, o); s2 += __shfl_down(s2, o); }
  __shared__ float as_[4], as2_[4];
  if ((t & 63) == 0) { as_[t >> 6] = s; as2_[t >> 6] = s2; }
  __syncthreads();
  s = as_[0] + as_[1] + as_[2] + as_[3];
  s2 = as2_[0] + as2_[1] + as2_[2] + as2_[3];
  float mean = s * (1.f / 768.f);
  float var = s2 * (1.f / 768.f) - mean * mean;
  float r = rsqrtf(var + 1e-5f);
  st_ln(&yr[t],       (v0 - mean) * r * g[t]       + b[t]);
  st_ln(&yr[t + 256], (v1 - mean) * r * g[t + 256] + b[t + 256]);
  st_ln(&yr[t + 512], (v2 - mean) * r * g[t + 512] + b[t + 512]);
}

// ---------------- patch extraction ----------------
__global__ __launch_bounds__(256) void im2col_k(const float* __restrict__ x,
    short* __restrict__ A)
{
  int i = blockIdx.x * 256 + threadIdx.x;
  int k = i & 255, row = i >> 8;
  int px = k & 15, py = k >> 4;
  int gx = row & 31, gy = (row >> 5) & 31, b = row >> 10;
  A[i] = f2bf(x[((long)(b * 512) + gy * 16 + py) * 512 + gx * 16 + px]);
}

// ---------------- t = concat(cls, tok) + pos ----------------
__global__ __launch_bounds__(256) void assemble_k(const short* __restrict__ tok,
    const float* __restrict__ cls, const float* __restrict__ pos, float* __restrict__ t)
{
  int i = blockIdx.x * 256 + threadIdx.x;
  int d = i % 768; int rn = i / 768; int n = rn % 1025; int b = rn / 1025;
  float v = (n == 0) ? cls[d] : bf2f(tok[((long)(b * 1024 + n - 1)) * 768 + d]);
  t[i] = v + pos[n * 768 + d];
}

extern "C" void kernel_launch(void* const* d_in, const int* in_sizes, int n_in,
                              void* d_out, int out_size, void* d_ws, size_t ws_size,
                              hipStream_t stream)
{
  const float* x       = (const float*)d_in[0];
  const float* conv_w  = (const float*)d_in[1];
  const float* conv_b  = (const float*)d_in[2];
  const float* cls     = (const float*)d_in[3];
  const float* pos     = (const float*)d_in[4];
  const float* qkv_w   = (const float*)d_in[5];
  const float* merge_w = (const float*)d_in[6];
  const float* merge_b = (const float*)d_in[7];
  const float* ln1_s   = (const float*)d_in[8];
  const float* ln1_b   = (const float*)d_in[9];
  const float* ln2_s   = (const float*)d_in[10];
  const float* ln2_b   = (const float*)d_in[11];
  const float* ffn_w1  = (const float*)d_in[12];
  const float* ffn_b1  = (const float*)d_in[13];
  const float* ffn_w2  = (const float*)d_in[14];
  const float* ffn_b2  = (const float*)d_in[15];
  const float* lnf_s   = (const float*)d_in[16];
  const float* lnf_b   = (const float*)d_in[17];

  char* wsp = (char*)d_ws;
  size_t o = 0;
  auto take = [&](size_t bytes) { char* r = wsp + o; o = (o + bytes + 255) & ~(size_t)255; return r; };
  short* wq   = (short*)take(1536ul * 768 * 2);
  short* wm   = (short*)take(768ul * 512 * 2);
  short* wf1  = (short*)take(2048ul * 768 * 2);
  short* wf2  = (short*)take(768ul * 2048 * 2);
  short* wcv  = (short*)take(768ul * 256 * 2);
  float* t    = (float*)take(4100ul * 768 * 4);
  char*  hO   = take(4352ul * 768 * 2);              // h bf16 OR O bf16 (rows padded)
  short* qkv  = (short*)take(4ul * 1025 * 1536 * 2);
  char*  fV   = take(4352ul * 2048 * 2);             // f (padded) OR (im2col + tok)
  take(2ul << 20);                                   // slack

  short* h   = (short*)hO;
  short* O   = (short*)hO;
  short* f   = (short*)fV;
  short* imc = (short*)fV;
  short* tok = (short*)(fV + 4096ul * 256 * 2);

  dim3 blk(256);

  // ---- patch embed ----
  cvt_k<<<768, blk, 0, stream>>>(conv_w, wcv, 768 * 256);
  im2col_k<<<4096, blk, 0, stream>>>(x, imc);
  gemm64<<<dim3(6, 64), blk, 0, stream>>>(imc, wcv, tok, conv_b,
      4096, 768, 256, 256, 256, 768, 1 | 8);
  assemble_k<<<12300, blk, 0, stream>>>(tok, cls, pos, t);

  for (int i = 0; i < 12; ++i) {
    tconv4_k<<<4608, blk, 0, stream>>>(
        qkv_w + (long)i * 768 * 1536, merge_w + (long)i * 512 * 768,
        ffn_w1 + (long)i * 768 * 2048, ffn_w2 + (long)i * 2048 * 768,
        wq, wm, wf1, wf2);

    // h = LN1(t)
    ln_k<short><<<4100, blk, 0, stream>>>(t, ln1_s + i * 768, ln1_b + i * 768, h, 4100);
    // qkv = h @ qkv_w
    gemm64<<<dim3(12, 65), blk, 0, stream>>>(h, wq, qkv, nullptr,
        4100, 1536, 768, 768, 768, 1536, 8);
    // fused attention -> O
    flash_k<<<544, blk, 0, stream>>>(qkv, O);
    // t += O @ merge_w + merge_b
    gemm64<<<dim3(6, 65), blk, 0, stream>>>(O, wm, t, merge_b + i * 768,
        4100, 768, 512, 512, 512, 768, 1 | 4);
    // h = LN2(t)
    ln_k<short><<<4100, blk, 0, stream>>>(t, ln2_s + i * 768, ln2_b + i * 768, h, 4100);
    // f = GELU(h @ ffn_w1 + b1)
    gemm64<<<dim3(16, 65), blk, 0, stream>>>(h, wf1, f, ffn_b1 + i * 2048,
        4100, 2048, 768, 768, 768, 2048, 1 | 2 | 8);
    // t += f @ ffn_w2 + b2
    gemm64<<<dim3(6, 65), blk, 0, stream>>>(f, wf2, t, ffn_b2 + i * 768,
        4100, 768, 2048, 2048, 2048, 768, 1 | 4);
  }
  ln_k<float><<<4100, blk, 0, stream>>>(t, lnf_s, lnf_b, (float*)d_out, 4100);
}

// Round 6
// 2452.447 us; speedup vs baseline: 1.8309x; 1.0346x over previous
//
#include <hip/hip_runtime.h>

#define DEV __device__ __forceinline__

typedef short s8v __attribute__((ext_vector_type(8)));
typedef float f4v __attribute__((ext_vector_type(4)));

DEV short f2bf(float f) {
  unsigned u = __float_as_uint(f);
  u += 0x7FFFu + ((u >> 16) & 1u);
  return (short)(u >> 16);
}
DEV float bf2f(short s) { return __uint_as_float(((unsigned)(unsigned short)s) << 16); }

DEV void gld_lds16(const short* g, short* l) {
  __builtin_amdgcn_global_load_lds(
      (const __attribute__((address_space(1))) void*)g,
      (__attribute__((address_space(3))) void*)l, 16, 0, 0);
}

// XCD-bijective swizzle (m204)
DEV int xcd_swz(int id, int nwg) {
  int q8 = nwg >> 3, r8 = nwg & 7, xcd = id & 7, off = id >> 3;
  return (xcd < r8) ? (xcd * (q8 + 1) + off) : (r8 * (q8 + 1) + (xcd - r8) * q8 + off);
}

// ================= 64x128 tile bf16 BT GEMM, dbuf + chunk-swizzle =================
// C[M,N] = epi(A[M,K] @ B[N,K]^T). A,B bf16 row-major (%8 lda/ldb).
// Requires N%128==0, K%64==0; A readable through row ceil(M/64)*64.
// LDS slot (row, c) holds global chunk (row, c^(row&7)) -> conflict-free b128 reads.
// flags: 1=+bias[col], 2=exact GELU, 4=accumulate into fp32 C, 8=bf16 out
__global__ __launch_bounds__(256) void gemm64(
    const short* __restrict__ A, const short* __restrict__ B, void* __restrict__ Cv,
    const float* __restrict__ bias,
    int M, int N, int K, int lda, int ldb, int ldc, int flags)
{
  __shared__ __align__(16) short As[2][64 * 64];    // 16 KB
  __shared__ __align__(16) short Bs[2][128 * 64];   // 32 KB
  int nwg = gridDim.x * gridDim.y;
  int idl = blockIdx.y * gridDim.x + blockIdx.x;
  int swz = xcd_swz(idl, nwg);
  int bx = swz % gridDim.x, by = swz / gridDim.x;
  int m0 = by * 64, n0 = bx * 128;
  int tid = threadIdx.x, lane = tid & 63, w = tid >> 6;
  int lr = lane & 15, kg = lane >> 4;
  f4v acc[4][2] = {};
  int NT = K >> 6;

#define STAGE(bufi, k0)                                                   \
  {                                                                       \
    _Pragma("unroll")                                                     \
    for (int p = 0; p < 2; ++p) {                                         \
      int ch = p * 256 + w * 64 + lane;                                   \
      int row = ch >> 3, c = (ch & 7) ^ (row & 7);                        \
      gld_lds16(A + (long)(m0 + row) * lda + (k0) + c * 8,                \
                &As[bufi][(p * 256 + w * 64) * 8]);                       \
    }                                                                     \
    _Pragma("unroll")                                                     \
    for (int p = 0; p < 4; ++p) {                                         \
      int ch = p * 256 + w * 64 + lane;                                   \
      int row = ch >> 3, c = (ch & 7) ^ (row & 7);                        \
      gld_lds16(B + (long)(n0 + row) * ldb + (k0) + c * 8,                \
                &Bs[bufi][(p * 256 + w * 64) * 8]);                       \
    }                                                                     \
  }

  STAGE(0, 0)
  for (int t = 0; t < NT; ++t) {
    int buf = t & 1;
    if (t + 1 < NT) {
      STAGE(buf ^ 1, (t + 1) * 64)
      asm volatile("s_waitcnt vmcnt(6)" ::: "memory");   // retire tile-t loads only
    } else {
      asm volatile("s_waitcnt vmcnt(0)" ::: "memory");
    }
    __builtin_amdgcn_s_barrier();
    #pragma unroll
    for (int ks = 0; ks < 2; ++ks) {
      s8v av[4], bv[2];
      #pragma unroll
      for (int mi = 0; mi < 4; ++mi) {
        int row = mi * 16 + lr;
        int sl = (ks * 4 + kg) ^ (row & 7);
        av[mi] = *(const s8v*)&As[buf][row * 64 + sl * 8];
      }
      #pragma unroll
      for (int ni = 0; ni < 2; ++ni) {
        int row = w * 32 + ni * 16 + lr;
        int sl = (ks * 4 + kg) ^ (row & 7);
        bv[ni] = *(const s8v*)&Bs[buf][row * 64 + sl * 8];
      }
      #pragma unroll
      for (int mi = 0; mi < 4; ++mi)
        #pragma unroll
        for (int ni = 0; ni < 2; ++ni)
          acc[mi][ni] = __builtin_amdgcn_mfma_f32_16x16x32_bf16(av[mi], bv[ni], acc[mi][ni], 0, 0, 0);
    }
    asm volatile("s_waitcnt lgkmcnt(0)" ::: "memory");   // my ds_reads retired
    __builtin_amdgcn_s_barrier();                        // safe to overwrite buf next iter
  }
#undef STAGE

  float* Cf = (float*)Cv;
  short* Cb = (short*)Cv;
  #pragma unroll
  for (int mi = 0; mi < 4; ++mi)
    #pragma unroll
    for (int ni = 0; ni < 2; ++ni) {
      int col = n0 + w * 32 + ni * 16 + lr;
      float bvv = (flags & 1) ? bias[col] : 0.f;
      #pragma unroll
      for (int j = 0; j < 4; ++j) {
        int row = m0 + mi * 16 + kg * 4 + j;
        if (row >= M) continue;
        float v = acc[mi][ni][j] + bvv;
        if (flags & 2) v = 0.5f * v * (1.f + erff(v * 0.70710678118f));
        long ci = (long)row * ldc + col;
        if (flags & 8) Cb[ci] = f2bf(v);
        else { if (flags & 4) v += Cf[ci]; Cf[ci] = v; }
      }
    }
}

// ---------------- fused flash attention (dbuf K/V) ----------------
// qkv: [4][1025][1536] bf16 (Q +0, K +64, V +128 per head zh*192)
// O:   [4][1025][512]  bf16
__global__ __launch_bounds__(256) void flash_k(
    const short* __restrict__ qkv, short* __restrict__ O)
{
  int swz = xcd_swz(blockIdx.x, 544);
  int z = swz / 17, qt = swz - z * 17;
  int zb = z >> 3, zh = z & 7;
  const short* base = qkv + (long)zb * 1025 * 1536 + zh * 192;
  const short* Qg = base;
  const short* Kg = base + 64;
  const short* Vg = base + 128;
  int q0 = qt * 64;
  int tid = threadIdx.x, lane = tid & 63, w = tid >> 6;
  int lr = lane & 15, kg = lane >> 4;

  __shared__ __align__(16) short Qs[64][72];
  __shared__ __align__(16) short Ks[2][64 * 64];
  __shared__ __align__(16) short Vt[2][64][72];
  __shared__ __align__(16) short Ps[4][16][72];

  // stage Q (bounds-checked, zero-fill)
  for (int s = tid; s < 512; s += 256) {
    int row = s >> 3, ch = s & 7;
    s8v v = {};
    if (q0 + row < 1025) v = *(const s8v*)(Qg + (long)(q0 + row) * 1536 + ch * 8);
    *(s8v*)&Qs[row][ch * 8] = v;
  }
  __syncthreads();
  s8v aq[2];
  aq[0] = *(const s8v*)&Qs[w * 16 + lr][kg * 8];
  aq[1] = *(const s8v*)&Qs[w * 16 + lr][32 + kg * 8];

  // K staging: 2 gld_lds/wave, chunk-swizzled slots
#define STAGE_K(bufi, kv0)                                                 \
  {                                                                        \
    int s0 = w * 128;                                                      \
    _Pragma("unroll")                                                      \
    for (int i = 0; i < 2; ++i) {                                          \
      int s = s0 + i * 64 + lane;                                          \
      int row = s >> 3, c = (s & 7) ^ (row & 7);                           \
      gld_lds16(Kg + (long)((kv0) + row) * 1536 + c * 8,                   \
                &Ks[bufi][(s0 + i * 64) * 8]);                             \
    }                                                                      \
  }

  f4v acc[4] = {};
  float m_run[4], l_run[4];
  #pragma unroll
  for (int j = 0; j < 4; ++j) { m_run[j] = -3.0e38f; l_run[j] = 0.f; }

  // ---- prologue: stage tile 0 ----
  STAGE_K(0, 0)
  {
    #pragma unroll
    for (int p = 0; p < 2; ++p) {
      int s = p * 256 + tid;
      int key = s & 63, ch = s >> 6;
      s8v v = {};
      if (key < 1025) v = *(const s8v*)(Vg + (long)key * 1536 + ch * 8);
      #pragma unroll
      for (int j = 0; j < 8; ++j) Vt[0][ch * 8 + j][key] = v[j];
    }
  }
  asm volatile("s_waitcnt vmcnt(0)" ::: "memory");
  asm volatile("s_waitcnt lgkmcnt(0)" ::: "memory");
  __builtin_amdgcn_s_barrier();

  for (int kt = 0; kt < 17; ++kt) {
    int cur = kt & 1;
    int kv0 = kt * 64;
    // issue next tile's stages early (land during compute)
    s8v vreg[2];
    int vok[2];
    if (kt < 16) {
      STAGE_K(cur ^ 1, kv0 + 64)
      #pragma unroll
      for (int p = 0; p < 2; ++p) {
        int s = p * 256 + tid;
        int key = (s & 63) + kv0 + 64, ch = s >> 6;
        vok[p] = key < 1025;
        vreg[p] = vok[p] ? *(const s8v*)(Vg + (long)key * 1536 + ch * 8) : s8v{};
      }
    }

    // S = Q K^T (swizzled K reads)
    f4v sa[4] = {};
    #pragma unroll
    for (int ni = 0; ni < 4; ++ni) {
      int row = ni * 16 + lr;
      #pragma unroll
      for (int ks = 0; ks < 2; ++ks) {
        int c = (ks * 4 + kg) ^ (row & 7);
        s8v bk = *(const s8v*)&Ks[cur][row * 64 + c * 8];
        sa[ni] = __builtin_amdgcn_mfma_f32_16x16x32_bf16(aq[ks], bk, sa[ni], 0, 0, 0);
      }
    }
    // mask + online softmax
    float sv[4][4], pv[4][4], tm[4], ts[4];
    #pragma unroll
    for (int j = 0; j < 4; ++j) tm[j] = -3.0e38f;
    #pragma unroll
    for (int ni = 0; ni < 4; ++ni) {
      bool valid = (kv0 + ni * 16 + lr) < 1025;
      #pragma unroll
      for (int j = 0; j < 4; ++j) {
        float s = valid ? sa[ni][j] * 0.125f : -3.0e38f;
        sv[ni][j] = s;
        tm[j] = fmaxf(tm[j], s);
      }
    }
    #pragma unroll
    for (int o = 1; o < 16; o <<= 1)
      #pragma unroll
      for (int j = 0; j < 4; ++j) tm[j] = fmaxf(tm[j], __shfl_xor(tm[j], o));
    float scale[4], m_new[4];
    #pragma unroll
    for (int j = 0; j < 4; ++j) {
      m_new[j] = fmaxf(m_run[j], tm[j]);
      scale[j] = __expf(m_run[j] - m_new[j]);
      m_run[j] = m_new[j];
      ts[j] = 0.f;
    }
    #pragma unroll
    for (int ni = 0; ni < 4; ++ni)
      #pragma unroll
      for (int j = 0; j < 4; ++j) {
        float p = __expf(sv[ni][j] - m_new[j]);
        pv[ni][j] = p;
        ts[j] += p;
      }
    #pragma unroll
    for (int o = 1; o < 16; o <<= 1)
      #pragma unroll
      for (int j = 0; j < 4; ++j) ts[j] += __shfl_xor(ts[j], o);
    #pragma unroll
    for (int j = 0; j < 4; ++j) l_run[j] = l_run[j] * scale[j] + ts[j];
    #pragma unroll
    for (int ni = 0; ni < 4; ++ni)
      #pragma unroll
      for (int j = 0; j < 4; ++j) acc[ni][j] *= scale[j];

    // write next tile's V (reg loads auto-waited here; hides under softmax above)
    if (kt < 16) {
      #pragma unroll
      for (int p = 0; p < 2; ++p) {
        int s = p * 256 + tid;
        int key = s & 63, ch = s >> 6;
        s8v v = vok[p] ? vreg[p] : s8v{};
        #pragma unroll
        for (int j = 0; j < 8; ++j) Vt[cur ^ 1][ch * 8 + j][key] = v[j];
      }
    }

    // P -> per-wave LDS
    #pragma unroll
    for (int ni = 0; ni < 4; ++ni)
      #pragma unroll
      for (int j = 0; j < 4; ++j)
        Ps[w][kg * 4 + j][ni * 16 + lr] = f2bf(pv[ni][j]);
    asm volatile("s_waitcnt lgkmcnt(0)" ::: "memory");
    // O += P V
    s8v ap[2];
    ap[0] = *(const s8v*)&Ps[w][lr][kg * 8];
    ap[1] = *(const s8v*)&Ps[w][lr][32 + kg * 8];
    #pragma unroll
    for (int ni = 0; ni < 4; ++ni) {
      #pragma unroll
      for (int ks = 0; ks < 2; ++ks) {
        s8v bvv = *(const s8v*)&Vt[cur][ni * 16 + lr][ks * 32 + kg * 8];
        acc[ni] = __builtin_amdgcn_mfma_f32_16x16x32_bf16(ap[ks], bvv, acc[ni], 0, 0, 0);
      }
    }
    // end-of-iter: my ds ops retired; next-tile K loads landed; then barrier
    asm volatile("s_waitcnt lgkmcnt(0)" ::: "memory");
    asm volatile("s_waitcnt vmcnt(0)" ::: "memory");
    __builtin_amdgcn_s_barrier();
  }
#undef STAGE_K

  float inv[4];
  #pragma unroll
  for (int j = 0; j < 4; ++j) inv[j] = 1.f / l_run[j];
  #pragma unroll
  for (int ni = 0; ni < 4; ++ni)
    #pragma unroll
    for (int j = 0; j < 4; ++j) {
      int row = q0 + w * 16 + kg * 4 + j;
      if (row < 1025)
        O[((long)(zb * 1025 + row)) * 512 + zh * 64 + ni * 16 + lr] = f2bf(acc[ni][j] * inv[j]);
    }
}

// ---------------- fused per-layer weight transpose+convert ----------------
DEV void tconv_body(const float* w, short* wt, int K, int N, int bx, int by, int tid)
{
  __shared__ float tile[32][33];
  int n0 = bx * 32, k0 = by * 32;
  int tx = tid & 31, ty = tid >> 5;
  #pragma unroll
  for (int j = 0; j < 4; ++j)
    tile[ty + j * 8][tx] = w[(long)(k0 + ty + j * 8) * N + n0 + tx];
  __syncthreads();
  #pragma unroll
  for (int j = 0; j < 4; ++j)
    wt[(long)(n0 + ty + j * 8) * K + k0 + tx] = f2bf(tile[tx][ty + j * 8]);
}

__global__ __launch_bounds__(256) void tconv4_k(
    const float* __restrict__ sq, const float* __restrict__ sm,
    const float* __restrict__ sf1, const float* __restrict__ sf2,
    short* __restrict__ dq, short* __restrict__ dm,
    short* __restrict__ df1, short* __restrict__ df2)
{
  int id = blockIdx.x, tid = threadIdx.x;
  if (id < 1152)       tconv_body(sq,  dq,  768, 1536, id % 48,          id / 48,          tid);
  else if (id < 1536)  tconv_body(sm,  dm,  512, 768,  (id - 1152) % 24, (id - 1152) / 24, tid);
  else if (id < 3072)  tconv_body(sf1, df1, 768, 2048, (id - 1536) % 64, (id - 1536) / 64, tid);
  else                 tconv_body(sf2, df2, 2048, 768, (id - 3072) % 24, (id - 3072) / 24, tid);
}

// ---------------- elementwise fp32 -> bf16 ----------------
__global__ __launch_bounds__(256) void cvt_k(const float* __restrict__ in,
    short* __restrict__ out, int n)
{
  int i = blockIdx.x * 256 + threadIdx.x;
  if (i < n) out[i] = f2bf(in[i]);
}

// ---------------- LayerNorm D=768 ----------------
DEV void st_ln(float* p, float v) { *p = v; }
DEV void st_ln(short* p, float v) { *p = f2bf(v); }

template<typename OT>
__global__ __launch_bounds__(256) void ln_k(const float* __restrict__ x,
    const float* __restrict__ g, const float* __restrict__ b,
    OT* __restrict__ y, int rows)
{
  int row = blockIdx.x;
  if (row >= rows) return;
  const float* xr = x + (long)row * 768;
  OT* yr = y + (long)row * 768;
  int t = threadIdx.x;
  float v0 = xr[t], v1 = xr[t + 256], v2 = xr[t + 512];
  float s = v0 + v1 + v2, s2 = v0 * v0 + v1 * v1 + v2 * v2;
  #pragma unroll
  for (int o = 32; o > 0; o >>= 1) { s += __shfl_down(s, o); s2 += __shfl_down(s2, o); }
  __shared__ float as_[4], as2_[4];
  if ((t & 63) == 0) { as_[t >> 6] = s; as2_[t >> 6] = s2; }
  __syncthreads();
  s = as_[0] + as_[1] + as_[2] + as_[3];
  s2 = as2_[0] + as2_[1] + as2_[2] + as2_[3];
  float mean = s * (1.f / 768.f);
  float var = s2 * (1.f / 768.f) - mean * mean;
  float r = rsqrtf(var + 1e-5f);
  st_ln(&yr[t],       (v0 - mean) * r * g[t]       + b[t]);
  st_ln(&yr[t + 256], (v1 - mean) * r * g[t + 256] + b[t + 256]);
  st_ln(&yr[t + 512], (v2 - mean) * r * g[t + 512] + b[t + 512]);
}

// ---------------- patch extraction ----------------
__global__ __launch_bounds__(256) void im2col_k(const float* __restrict__ x,
    short* __restrict__ A)
{
  int i = blockIdx.x * 256 + threadIdx.x;
  int k = i & 255, row = i >> 8;
  int px = k & 15, py = k >> 4;
  int gx = row & 31, gy = (row >> 5) & 31, b = row >> 10;
  A[i] = f2bf(x[((long)(b * 512) + gy * 16 + py) * 512 + gx * 16 + px]);
}

// ---------------- t = concat(cls, tok) + pos ----------------
__global__ __launch_bounds__(256) void assemble_k(const short* __restrict__ tok,
    const float* __restrict__ cls, const float* __restrict__ pos, float* __restrict__ t)
{
  int i = blockIdx.x * 256 + threadIdx.x;
  int d = i % 768; int rn = i / 768; int n = rn % 1025; int b = rn / 1025;
  float v = (n == 0) ? cls[d] : bf2f(tok[((long)(b * 1024 + n - 1)) * 768 + d]);
  t[i] = v + pos[n * 768 + d];
}

extern "C" void kernel_launch(void* const* d_in, const int* in_sizes, int n_in,
                              void* d_out, int out_size, void* d_ws, size_t ws_size,
                              hipStream_t stream)
{
  const float* x       = (const float*)d_in[0];
  const float* conv_w  = (const float*)d_in[1];
  const float* conv_b  = (const float*)d_in[2];
  const float* cls     = (const float*)d_in[3];
  const float* pos     = (const float*)d_in[4];
  const float* qkv_w   = (const float*)d_in[5];
  const float* merge_w = (const float*)d_in[6];
  const float* merge_b = (const float*)d_in[7];
  const float* ln1_s   = (const float*)d_in[8];
  const float* ln1_b   = (const float*)d_in[9];
  const float* ln2_s   = (const float*)d_in[10];
  const float* ln2_b   = (const float*)d_in[11];
  const float* ffn_w1  = (const float*)d_in[12];
  const float* ffn_b1  = (const float*)d_in[13];
  const float* ffn_w2  = (const float*)d_in[14];
  const float* ffn_b2  = (const float*)d_in[15];
  const float* lnf_s   = (const float*)d_in[16];
  const float* lnf_b   = (const float*)d_in[17];

  char* wsp = (char*)d_ws;
  size_t o = 0;
  auto take = [&](size_t bytes) { char* r = wsp + o; o = (o + bytes + 255) & ~(size_t)255; return r; };
  short* wq   = (short*)take(1536ul * 768 * 2);
  short* wm   = (short*)take(768ul * 512 * 2);
  short* wf1  = (short*)take(2048ul * 768 * 2);
  short* wf2  = (short*)take(768ul * 2048 * 2);
  short* wcv  = (short*)take(768ul * 256 * 2);
  float* t    = (float*)take(4100ul * 768 * 4);
  char*  hO   = take(4352ul * 768 * 2);              // h bf16 OR O bf16 (rows padded)
  short* qkv  = (short*)take(4ul * 1025 * 1536 * 2);
  char*  fV   = take(4352ul * 2048 * 2);             // f (padded) OR (im2col + tok)
  take(2ul << 20);                                   // slack for tile over-reads

  short* h   = (short*)hO;
  short* O   = (short*)hO;
  short* f   = (short*)fV;
  short* imc = (short*)fV;
  short* tok = (short*)(fV + 4096ul * 256 * 2);

  dim3 blk(256);

  // ---- patch embed ----
  cvt_k<<<768, blk, 0, stream>>>(conv_w, wcv, 768 * 256);
  im2col_k<<<4096, blk, 0, stream>>>(x, imc);
  gemm64<<<dim3(6, 64), blk, 0, stream>>>(imc, wcv, tok, conv_b,
      4096, 768, 256, 256, 256, 768, 1 | 8);
  assemble_k<<<12300, blk, 0, stream>>>(tok, cls, pos, t);

  for (int i = 0; i < 12; ++i) {
    tconv4_k<<<4608, blk, 0, stream>>>(
        qkv_w + (long)i * 768 * 1536, merge_w + (long)i * 512 * 768,
        ffn_w1 + (long)i * 768 * 2048, ffn_w2 + (long)i * 2048 * 768,
        wq, wm, wf1, wf2);

    // h = LN1(t)
    ln_k<short><<<4100, blk, 0, stream>>>(t, ln1_s + i * 768, ln1_b + i * 768, h, 4100);
    // qkv = h @ qkv_w
    gemm64<<<dim3(12, 65), blk, 0, stream>>>(h, wq, qkv, nullptr,
        4100, 1536, 768, 768, 768, 1536, 8);
    // fused attention -> O
    flash_k<<<544, blk, 0, stream>>>(qkv, O);
    // t += O @ merge_w + merge_b
    gemm64<<<dim3(6, 65), blk, 0, stream>>>(O, wm, t, merge_b + i * 768,
        4100, 768, 512, 512, 512, 768, 1 | 4);
    // h = LN2(t)
    ln_k<short><<<4100, blk, 0, stream>>>(t, ln2_s + i * 768, ln2_b + i * 768, h, 4100);
    // f = GELU(h @ ffn_w1 + b1)
    gemm64<<<dim3(16, 65), blk, 0, stream>>>(h, wf1, f, ffn_b1 + i * 2048,
        4100, 2048, 768, 768, 768, 2048, 1 | 2 | 8);
    // t += f @ ffn_w2 + b2
    gemm64<<<dim3(6, 65), blk, 0, stream>>>(f, wf2, t, ffn_b2 + i * 768,
        4100, 768, 2048, 2048, 2048, 768, 1 | 4);
  }
  ln_k<float><<<4100, blk, 0, stream>>>(t, lnf_s, lnf_b, (float*)d_out, 4100);
}

// Round 7
// 2319.910 us; speedup vs baseline: 1.9355x; 1.0571x over previous
//
#include <hip/hip_runtime.h>

#define DEV __device__ __forceinline__

typedef short s8v __attribute__((ext_vector_type(8)));
typedef float f4v __attribute__((ext_vector_type(4)));

DEV short f2bf(float f) {
  unsigned u = __float_as_uint(f);
  u += 0x7FFFu + ((u >> 16) & 1u);
  return (short)(u >> 16);
}
DEV float bf2f(short s) { return __uint_as_float(((unsigned)(unsigned short)s) << 16); }

DEV void gld_lds16(const short* g, short* l) {
  __builtin_amdgcn_global_load_lds(
      (const __attribute__((address_space(1))) void*)g,
      (__attribute__((address_space(3))) void*)l, 16, 0, 0);
}

// XCD-bijective swizzle (m204)
DEV int xcd_swz(int id, int nwg) {
  int q8 = nwg >> 3, r8 = nwg & 7, xcd = id & 7, off = id >> 3;
  return (xcd < r8) ? (xcd * (q8 + 1) + off) : (r8 * (q8 + 1) + (xcd - r8) * q8 + off);
}

// ================= 64xBN tile bf16 BT GEMM, dbuf + chunk-swizzle =================
// C[M,N] = epi(A[M,K] @ B[N,K]^T). BN=128: waves 1x4 (64x32 each). BN=64: waves 2x2 (32x32).
// LDS slot (row,c) holds global chunk (row, c^(row&7)) -> conflict-free b128 reads.
// flags: 1=+bias[col], 2=exact GELU, 4=accumulate into fp32 C, 8=bf16 out
template<int BN>
__global__ __launch_bounds__(256) void gemm_t(
    const short* __restrict__ A, const short* __restrict__ B, void* __restrict__ Cv,
    const float* __restrict__ bias,
    int M, int N, int K, int lda, int ldb, int ldc, int flags)
{
  constexpr int BPASS = BN / 32;                 // B staging passes
  constexpr int MI = (BN == 128) ? 4 : 2;        // M fragments per wave
  __shared__ __align__(16) short As[2][64 * 64];
  __shared__ __align__(16) short Bs[2][BN * 64];
  int nwg = gridDim.x * gridDim.y;
  int idl = blockIdx.y * gridDim.x + blockIdx.x;
  int swz = xcd_swz(idl, nwg);
  int bx = swz % gridDim.x, by = swz / gridDim.x;
  int m0 = by * 64, n0 = bx * BN;
  int tid = threadIdx.x, lane = tid & 63, w = tid >> 6;
  int lr = lane & 15, kg = lane >> 4;
  int wrb = (BN == 128) ? 0 : (w >> 1) * 32;
  int wcb = (BN == 128) ? w * 32 : (w & 1) * 32;
  f4v acc[MI][2] = {};
  int NT = K >> 6;

#define STAGE(bufi, k0)                                                   \
  {                                                                       \
    _Pragma("unroll")                                                     \
    for (int p = 0; p < 2; ++p) {                                         \
      int ch = p * 256 + w * 64 + lane;                                   \
      int row = ch >> 3, c = (ch & 7) ^ (row & 7);                        \
      gld_lds16(A + (long)(m0 + row) * lda + (k0) + c * 8,                \
                &As[bufi][(p * 256 + w * 64) * 8]);                       \
    }                                                                     \
    _Pragma("unroll")                                                     \
    for (int p = 0; p < BPASS; ++p) {                                     \
      int ch = p * 256 + w * 64 + lane;                                   \
      int row = ch >> 3, c = (ch & 7) ^ (row & 7);                        \
      gld_lds16(B + (long)(n0 + row) * ldb + (k0) + c * 8,                \
                &Bs[bufi][(p * 256 + w * 64) * 8]);                       \
    }                                                                     \
  }

  STAGE(0, 0)
  for (int t = 0; t < NT; ++t) {
    int buf = t & 1;
    if (t + 1 < NT) {
      STAGE(buf ^ 1, (t + 1) * 64)
      if constexpr (BN == 128)
        asm volatile("s_waitcnt vmcnt(6)" ::: "memory");   // retire tile-t loads only
      else
        asm volatile("s_waitcnt vmcnt(4)" ::: "memory");
    } else {
      asm volatile("s_waitcnt vmcnt(0)" ::: "memory");
    }
    __builtin_amdgcn_s_barrier();
    #pragma unroll
    for (int ks = 0; ks < 2; ++ks) {
      s8v av[MI], bv[2];
      #pragma unroll
      for (int mi = 0; mi < MI; ++mi) {
        int row = wrb + mi * 16 + lr;
        int sl = (ks * 4 + kg) ^ (row & 7);
        av[mi] = *(const s8v*)&As[buf][row * 64 + sl * 8];
      }
      #pragma unroll
      for (int ni = 0; ni < 2; ++ni) {
        int row = wcb + ni * 16 + lr;
        int sl = (ks * 4 + kg) ^ (row & 7);
        bv[ni] = *(const s8v*)&Bs[buf][row * 64 + sl * 8];
      }
      #pragma unroll
      for (int mi = 0; mi < MI; ++mi)
        #pragma unroll
        for (int ni = 0; ni < 2; ++ni)
          acc[mi][ni] = __builtin_amdgcn_mfma_f32_16x16x32_bf16(av[mi], bv[ni], acc[mi][ni], 0, 0, 0);
    }
    asm volatile("s_waitcnt lgkmcnt(0)" ::: "memory");
    __builtin_amdgcn_s_barrier();
  }
#undef STAGE

  float* Cf = (float*)Cv;
  short* Cb = (short*)Cv;
  #pragma unroll
  for (int mi = 0; mi < MI; ++mi)
    #pragma unroll
    for (int ni = 0; ni < 2; ++ni) {
      int col = n0 + wcb + ni * 16 + lr;
      float bvv = (flags & 1) ? bias[col] : 0.f;
      #pragma unroll
      for (int j = 0; j < 4; ++j) {
        int row = m0 + wrb + mi * 16 + kg * 4 + j;
        if (row >= M) continue;
        float v = acc[mi][ni][j] + bvv;
        if (flags & 2) v = 0.5f * v * (1.f + erff(v * 0.70710678118f));
        long ci = (long)row * ldc + col;
        if (flags & 8) Cb[ci] = f2bf(v);
        else { if (flags & 4) v += Cf[ci]; Cf[ci] = v; }
      }
    }
}

// ---------------- fused flash attention, 2-way KV split ----------------
// qkv: [4][1025][1536] bf16 (Q +0, K +64, V +128 per head zh*192)
// Opart: [2][32][1025][64] fp32 unnormalized; ML: [2][32][1025][2] fp32 (m,l)
// grid 1088 = 2 halves * 32 z * 17 qtiles
__global__ __launch_bounds__(256) void flash_k(
    const short* __restrict__ qkv, float* __restrict__ Opart, float* __restrict__ ML)
{
  int swz = xcd_swz(blockIdx.x, 1088);
  int h = swz / 544, rem = swz - h * 544;
  int z = rem / 17, qt = rem - z * 17;
  int zb = z >> 3, zh = z & 7;
  const short* base = qkv + (long)zb * 1025 * 1536 + zh * 192;
  const short* Qg = base;
  const short* Kg = base + 64;
  const short* Vg = base + 128;
  int q0 = qt * 64;
  int kt0 = h * 9, kt_end = h ? 17 : 9;
  int tid = threadIdx.x, lane = tid & 63, w = tid >> 6;
  int lr = lane & 15, kg = lane >> 4;

  __shared__ __align__(16) short QPs[64][72];   // Q in prologue; per-wave P after
  __shared__ __align__(16) short Ks[2][64 * 64];
  __shared__ __align__(16) short Vt[2][64][72];

  // stage Q (bounds-checked, zero-fill)
  for (int s = tid; s < 512; s += 256) {
    int row = s >> 3, ch = s & 7;
    s8v v = {};
    if (q0 + row < 1025) v = *(const s8v*)(Qg + (long)(q0 + row) * 1536 + ch * 8);
    *(s8v*)&QPs[row][ch * 8] = v;
  }
  __syncthreads();
  s8v aq[2];
  aq[0] = *(const s8v*)&QPs[w * 16 + lr][kg * 8];
  aq[1] = *(const s8v*)&QPs[w * 16 + lr][32 + kg * 8];

#define STAGE_K(bufi, kv0)                                                 \
  {                                                                        \
    int s0 = w * 128;                                                      \
    _Pragma("unroll")                                                      \
    for (int i = 0; i < 2; ++i) {                                          \
      int s = s0 + i * 64 + lane;                                          \
      int row = s >> 3, c = (s & 7) ^ (row & 7);                           \
      gld_lds16(Kg + (long)((kv0) + row) * 1536 + c * 8,                   \
                &Ks[bufi][(s0 + i * 64) * 8]);                             \
    }                                                                      \
  }

  f4v acc[4] = {};
  float m_run[4], l_run[4];
  #pragma unroll
  for (int j = 0; j < 4; ++j) { m_run[j] = -3.0e38f; l_run[j] = 0.f; }

  // ---- prologue: stage tile kt0 (keys <= 639, always valid) ----
  STAGE_K(0, kt0 * 64)
  #pragma unroll
  for (int p = 0; p < 2; ++p) {
    int s = p * 256 + tid;
    int key = s & 63, ch = s >> 6;
    s8v v = *(const s8v*)(Vg + (long)(kt0 * 64 + key) * 1536 + ch * 8);
    #pragma unroll
    for (int j = 0; j < 8; ++j) Vt[0][ch * 8 + j][key] = v[j];
  }
  asm volatile("s_waitcnt vmcnt(0)" ::: "memory");
  asm volatile("s_waitcnt lgkmcnt(0)" ::: "memory");
  __builtin_amdgcn_s_barrier();

  for (int kt = kt0; kt < kt_end; ++kt) {
    int cur = (kt - kt0) & 1;
    int kv0 = kt * 64;
    s8v vreg[2];
    int vok[2];
    if (kt + 1 < kt_end) {
      STAGE_K(cur ^ 1, kv0 + 64)
      #pragma unroll
      for (int p = 0; p < 2; ++p) {
        int s = p * 256 + tid;
        int key = (s & 63) + kv0 + 64, ch = s >> 6;
        vok[p] = key < 1025;
        vreg[p] = vok[p] ? *(const s8v*)(Vg + (long)key * 1536 + ch * 8) : s8v{};
      }
    }

    // S = Q K^T (swizzled K reads)
    f4v sa[4] = {};
    #pragma unroll
    for (int ni = 0; ni < 4; ++ni) {
      int row = ni * 16 + lr;
      #pragma unroll
      for (int ks = 0; ks < 2; ++ks) {
        int c = (ks * 4 + kg) ^ (row & 7);
        s8v bk = *(const s8v*)&Ks[cur][row * 64 + c * 8];
        sa[ni] = __builtin_amdgcn_mfma_f32_16x16x32_bf16(aq[ks], bk, sa[ni], 0, 0, 0);
      }
    }
    // mask + online softmax
    float sv[4][4], pv[4][4], tm[4], ts[4];
    #pragma unroll
    for (int j = 0; j < 4; ++j) tm[j] = -3.0e38f;
    #pragma unroll
    for (int ni = 0; ni < 4; ++ni) {
      bool valid = (kv0 + ni * 16 + lr) < 1025;
      #pragma unroll
      for (int j = 0; j < 4; ++j) {
        float s = valid ? sa[ni][j] * 0.125f : -3.0e38f;
        sv[ni][j] = s;
        tm[j] = fmaxf(tm[j], s);
      }
    }
    #pragma unroll
    for (int o = 1; o < 16; o <<= 1)
      #pragma unroll
      for (int j = 0; j < 4; ++j) tm[j] = fmaxf(tm[j], __shfl_xor(tm[j], o));
    float scale[4], m_new[4];
    #pragma unroll
    for (int j = 0; j < 4; ++j) {
      m_new[j] = fmaxf(m_run[j], tm[j]);
      scale[j] = __expf(m_run[j] - m_new[j]);
      m_run[j] = m_new[j];
      ts[j] = 0.f;
    }
    #pragma unroll
    for (int ni = 0; ni < 4; ++ni)
      #pragma unroll
      for (int j = 0; j < 4; ++j) {
        float p = __expf(sv[ni][j] - m_new[j]);
        pv[ni][j] = p;
        ts[j] += p;
      }
    #pragma unroll
    for (int o = 1; o < 16; o <<= 1)
      #pragma unroll
      for (int j = 0; j < 4; ++j) ts[j] += __shfl_xor(ts[j], o);
    #pragma unroll
    for (int j = 0; j < 4; ++j) l_run[j] = l_run[j] * scale[j] + ts[j];
    #pragma unroll
    for (int ni = 0; ni < 4; ++ni)
      #pragma unroll
      for (int j = 0; j < 4; ++j) acc[ni][j] *= scale[j];

    // write next tile's V (reg loads auto-waited; hides under softmax)
    if (kt + 1 < kt_end) {
      #pragma unroll
      for (int p = 0; p < 2; ++p) {
        int s = p * 256 + tid;
        int key = s & 63, ch = s >> 6;
        s8v v = vok[p] ? vreg[p] : s8v{};
        #pragma unroll
        for (int j = 0; j < 8; ++j) Vt[cur ^ 1][ch * 8 + j][key] = v[j];
      }
    }

    // P -> per-wave LDS slice of QPs
    #pragma unroll
    for (int ni = 0; ni < 4; ++ni)
      #pragma unroll
      for (int j = 0; j < 4; ++j)
        QPs[w * 16 + kg * 4 + j][ni * 16 + lr] = f2bf(pv[ni][j]);
    asm volatile("s_waitcnt lgkmcnt(0)" ::: "memory");
    // O += P V
    s8v ap[2];
    ap[0] = *(const s8v*)&QPs[w * 16 + lr][kg * 8];
    ap[1] = *(const s8v*)&QPs[w * 16 + lr][32 + kg * 8];
    #pragma unroll
    for (int ni = 0; ni < 4; ++ni) {
      #pragma unroll
      for (int ks = 0; ks < 2; ++ks) {
        s8v bvv = *(const s8v*)&Vt[cur][ni * 16 + lr][ks * 32 + kg * 8];
        acc[ni] = __builtin_amdgcn_mfma_f32_16x16x32_bf16(ap[ks], bvv, acc[ni], 0, 0, 0);
      }
    }
    asm volatile("s_waitcnt lgkmcnt(0)" ::: "memory");
    asm volatile("s_waitcnt vmcnt(0)" ::: "memory");
    __builtin_amdgcn_s_barrier();
  }
#undef STAGE_K

  // epilogue: unnormalized partial + (m,l)
  #pragma unroll
  for (int ni = 0; ni < 4; ++ni)
    #pragma unroll
    for (int j = 0; j < 4; ++j) {
      int row = q0 + w * 16 + kg * 4 + j;
      if (row < 1025) {
        long rbase = (long)(h * 32 + z) * 1025 + row;
        Opart[rbase * 64 + ni * 16 + lr] = acc[ni][j];
        if (ni == 0 && lr == 0) {
          ML[rbase * 2]     = m_run[j];
          ML[rbase * 2 + 1] = l_run[j];
        }
      }
    }
}

// ---------------- combine the two KV halves -> O bf16 [4][1025][512] ----------------
__global__ __launch_bounds__(256) void fcomb_k(
    const float* __restrict__ Opart, const float* __restrict__ ML, short* __restrict__ O)
{
  int idx = blockIdx.x * 256 + threadIdx.x;   // 32*1025*64 = 2,099,200
  if (idx >= 32 * 1025 * 64) return;
  int d = idx & 63;
  int r = idx >> 6;                            // z*1025 + row
  int z = r / 1025, row = r - z * 1025;
  float m0 = ML[(long)r * 2], l0 = ML[(long)r * 2 + 1];
  float m1 = ML[(long)(32800 + r) * 2], l1 = ML[(long)(32800 + r) * 2 + 1];
  float M = fmaxf(m0, m1);
  float w0 = __expf(m0 - M), w1 = __expf(m1 - M);
  float inv = 1.f / (l0 * w0 + l1 * w1);
  float v = (Opart[(long)r * 64 + d] * w0 + Opart[(long)(32800 + r) * 64 + d] * w1) * inv;
  int zb = z >> 3, zh = z & 7;
  O[((long)(zb * 1025 + row)) * 512 + zh * 64 + d] = f2bf(v);
}

// ---------------- fused per-layer weight transpose+convert ----------------
DEV void tconv_body(const float* w, short* wt, int K, int N, int bx, int by, int tid)
{
  __shared__ float tile[32][33];
  int n0 = bx * 32, k0 = by * 32;
  int tx = tid & 31, ty = tid >> 5;
  #pragma unroll
  for (int j = 0; j < 4; ++j)
    tile[ty + j * 8][tx] = w[(long)(k0 + ty + j * 8) * N + n0 + tx];
  __syncthreads();
  #pragma unroll
  for (int j = 0; j < 4; ++j)
    wt[(long)(n0 + ty + j * 8) * K + k0 + tx] = f2bf(tile[tx][ty + j * 8]);
}

__global__ __launch_bounds__(256) void tconv4_k(
    const float* __restrict__ sq, const float* __restrict__ sm,
    const float* __restrict__ sf1, const float* __restrict__ sf2,
    short* __restrict__ dq, short* __restrict__ dm,
    short* __restrict__ df1, short* __restrict__ df2)
{
  int id = blockIdx.x, tid = threadIdx.x;
  if (id < 1152)       tconv_body(sq,  dq,  768, 1536, id % 48,          id / 48,          tid);
  else if (id < 1536)  tconv_body(sm,  dm,  512, 768,  (id - 1152) % 24, (id - 1152) / 24, tid);
  else if (id < 3072)  tconv_body(sf1, df1, 768, 2048, (id - 1536) % 64, (id - 1536) / 64, tid);
  else                 tconv_body(sf2, df2, 2048, 768, (id - 3072) % 24, (id - 3072) / 24, tid);
}

// ---------------- elementwise fp32 -> bf16 ----------------
__global__ __launch_bounds__(256) void cvt_k(const float* __restrict__ in,
    short* __restrict__ out, int n)
{
  int i = blockIdx.x * 256 + threadIdx.x;
  if (i < n) out[i] = f2bf(in[i]);
}

// ---------------- LayerNorm D=768 ----------------
DEV void st_ln(float* p, float v) { *p = v; }
DEV void st_ln(short* p, float v) { *p = f2bf(v); }

template<typename OT>
__global__ __launch_bounds__(256) void ln_k(const float* __restrict__ x,
    const float* __restrict__ g, const float* __restrict__ b,
    OT* __restrict__ y, int rows)
{
  int row = blockIdx.x;
  if (row >= rows) return;
  const float* xr = x + (long)row * 768;
  OT* yr = y + (long)row * 768;
  int t = threadIdx.x;
  float v0 = xr[t], v1 = xr[t + 256], v2 = xr[t + 512];
  float s = v0 + v1 + v2, s2 = v0 * v0 + v1 * v1 + v2 * v2;
  #pragma unroll
  for (int o = 32; o > 0; o >>= 1) { s += __shfl_down(s, o); s2 += __shfl_down(s2, o); }
  __shared__ float as_[4], as2_[4];
  if ((t & 63) == 0) { as_[t >> 6] = s; as2_[t >> 6] = s2; }
  __syncthreads();
  s = as_[0] + as_[1] + as_[2] + as_[3];
  s2 = as2_[0] + as2_[1] + as2_[2] + as2_[3];
  float mean = s * (1.f / 768.f);
  float var = s2 * (1.f / 768.f) - mean * mean;
  float r = rsqrtf(var + 1e-5f);
  st_ln(&yr[t],       (v0 - mean) * r * g[t]       + b[t]);
  st_ln(&yr[t + 256], (v1 - mean) * r * g[t + 256] + b[t + 256]);
  st_ln(&yr[t + 512], (v2 - mean) * r * g[t + 512] + b[t + 512]);
}

// ---------------- patch extraction ----------------
__global__ __launch_bounds__(256) void im2col_k(const float* __restrict__ x,
    short* __restrict__ A)
{
  int i = blockIdx.x * 256 + threadIdx.x;
  int k = i & 255, row = i >> 8;
  int px = k & 15, py = k >> 4;
  int gx = row & 31, gy = (row >> 5) & 31, b = row >> 10;
  A[i] = f2bf(x[((long)(b * 512) + gy * 16 + py) * 512 + gx * 16 + px]);
}

// ---------------- t = concat(cls, tok) + pos ----------------
__global__ __launch_bounds__(256) void assemble_k(const short* __restrict__ tok,
    const float* __restrict__ cls, const float* __restrict__ pos, float* __restrict__ t)
{
  int i = blockIdx.x * 256 + threadIdx.x;
  int d = i % 768; int rn = i / 768; int n = rn % 1025; int b = rn / 1025;
  float v = (n == 0) ? cls[d] : bf2f(tok[((long)(b * 1024 + n - 1)) * 768 + d]);
  t[i] = v + pos[n * 768 + d];
}

extern "C" void kernel_launch(void* const* d_in, const int* in_sizes, int n_in,
                              void* d_out, int out_size, void* d_ws, size_t ws_size,
                              hipStream_t stream)
{
  const float* x       = (const float*)d_in[0];
  const float* conv_w  = (const float*)d_in[1];
  const float* conv_b  = (const float*)d_in[2];
  const float* cls     = (const float*)d_in[3];
  const float* pos     = (const float*)d_in[4];
  const float* qkv_w   = (const float*)d_in[5];
  const float* merge_w = (const float*)d_in[6];
  const float* merge_b = (const float*)d_in[7];
  const float* ln1_s   = (const float*)d_in[8];
  const float* ln1_b   = (const float*)d_in[9];
  const float* ln2_s   = (const float*)d_in[10];
  const float* ln2_b   = (const float*)d_in[11];
  const float* ffn_w1  = (const float*)d_in[12];
  const float* ffn_b1  = (const float*)d_in[13];
  const float* ffn_w2  = (const float*)d_in[14];
  const float* ffn_b2  = (const float*)d_in[15];
  const float* lnf_s   = (const float*)d_in[16];
  const float* lnf_b   = (const float*)d_in[17];

  char* wsp = (char*)d_ws;
  size_t o = 0;
  auto take = [&](size_t bytes) { char* r = wsp + o; o = (o + bytes + 255) & ~(size_t)255; return r; };
  short* wq   = (short*)take(1536ul * 768 * 2);
  short* wm   = (short*)take(768ul * 512 * 2);
  short* wf1  = (short*)take(2048ul * 768 * 2);
  short* wf2  = (short*)take(768ul * 2048 * 2);
  short* wcv  = (short*)take(768ul * 256 * 2);
  float* t    = (float*)take(4100ul * 768 * 4);
  char*  hO   = take(4352ul * 768 * 2);              // h bf16 OR O bf16 (rows padded)
  short* qkv  = (short*)take(4ul * 1025 * 1536 * 2);
  char*  fV   = take(4352ul * 2048 * 2);             // f (padded) OR (im2col+tok) OR (Opart+ML)
  take(2ul << 20);                                   // slack for tile over-reads

  short* h     = (short*)hO;
  short* O     = (short*)hO;
  short* f     = (short*)fV;
  short* imc   = (short*)fV;
  short* tok   = (short*)(fV + 4096ul * 256 * 2);
  float* Opart = (float*)fV;                          // 2*32*1025*64*4 = 16,793,600 B
  float* ML    = (float*)(fV + 16793600);             // 2*32800*2*4   = 524,800 B

  dim3 blk(256);

  // ---- patch embed ----
  cvt_k<<<768, blk, 0, stream>>>(conv_w, wcv, 768 * 256);
  im2col_k<<<4096, blk, 0, stream>>>(x, imc);
  gemm_t<64><<<dim3(12, 64), blk, 0, stream>>>(imc, wcv, tok, conv_b,
      4096, 768, 256, 256, 256, 768, 1 | 8);
  assemble_k<<<12300, blk, 0, stream>>>(tok, cls, pos, t);

  for (int i = 0; i < 12; ++i) {
    tconv4_k<<<4608, blk, 0, stream>>>(
        qkv_w + (long)i * 768 * 1536, merge_w + (long)i * 512 * 768,
        ffn_w1 + (long)i * 768 * 2048, ffn_w2 + (long)i * 2048 * 768,
        wq, wm, wf1, wf2);

    // h = LN1(t)
    ln_k<short><<<4100, blk, 0, stream>>>(t, ln1_s + i * 768, ln1_b + i * 768, h, 4100);
    // qkv = h @ qkv_w
    gemm_t<128><<<dim3(12, 65), blk, 0, stream>>>(h, wq, qkv, nullptr,
        4100, 1536, 768, 768, 768, 1536, 8);
    // fused attention (2-way KV split) -> Opart/ML -> O
    flash_k<<<1088, blk, 0, stream>>>(qkv, Opart, ML);
    fcomb_k<<<8200, blk, 0, stream>>>(Opart, ML, O);
    // t += O @ merge_w + merge_b
    gemm_t<64><<<dim3(12, 65), blk, 0, stream>>>(O, wm, t, merge_b + i * 768,
        4100, 768, 512, 512, 512, 768, 1 | 4);
    // h = LN2(t)
    ln_k<short><<<4100, blk, 0, stream>>>(t, ln2_s + i * 768, ln2_b + i * 768, h, 4100);
    // f = GELU(h @ ffn_w1 + b1)
    gemm_t<128><<<dim3(16, 65), blk, 0, stream>>>(h, wf1, f, ffn_b1 + i * 2048,
        4100, 2048, 768, 768, 768, 2048, 1 | 2 | 8);
    // t += f @ ffn_w2 + b2
    gemm_t<64><<<dim3(12, 65), blk, 0, stream>>>(f, wf2, t, ffn_b2 + i * 768,
        4100, 768, 2048, 2048, 2048, 768, 1 | 4);
  }
  ln_k<float><<<4100, blk, 0, stream>>>(t, lnf_s, lnf_b, (float*)d_out, 4100);
}